// Round 3
// baseline (1094.090 us; speedup 1.0000x reference)
//
#include <hip/hip_runtime.h>
#include <cstdint>
#include <cstddef>

#define L_SEQ 1024
#define BATCH 8
#define DMODEL 1024
#define DINNER 2048
#define NSTATE 16
#define DTRANK 64
#define NQ 4000
#define NROWS (BATCH * L_SEQ)   // 8192
#define CH 32                   // scan chunk length
#define NCH (L_SEQ / CH)        // 32 chunks

typedef float f32x4 __attribute__((ext_vector_type(4)));
typedef __bf16 bf16x8 __attribute__((ext_vector_type(8)));

#define AS1 __attribute__((address_space(1)))
#define AS3 __attribute__((address_space(3)))

#define VMCNT(n) asm volatile("s_waitcnt vmcnt(" #n ")" ::: "memory")
#define LGKMCNT0() asm volatile("s_waitcnt lgkmcnt(0)" ::: "memory")
#define SBARRIER() asm volatile("s_barrier" ::: "memory")

__device__ __forceinline__ unsigned short f2bf(float f) {
  union { float f; unsigned int u; } c; c.f = f;
  unsigned int u = c.u;
  unsigned int r = u + 0x7fffu + ((u >> 16) & 1u);
  return (unsigned short)(r >> 16);
}

__device__ __forceinline__ float sigmoidf_(float x) { return 1.f / (1.f + expf(-x)); }

// ---------------- weight fp32 -> bf16 cast ----------------
__global__ void cast_bf16_k(const float* __restrict__ src, unsigned short* __restrict__ dst, int n) {
  int i = blockIdx.x * blockDim.x + threadIdx.x;
  if (i < n) dst[i] = f2bf(src[i]);
}

// ---------------- block reduction helper (256 threads, 4 waves) ----------------
__device__ __forceinline__ float blk_sum(float v, float* s) {
  #pragma unroll
  for (int o = 32; o > 0; o >>= 1) v += __shfl_down(v, o, 64);
  int w = threadIdx.x >> 6;
  if ((threadIdx.x & 63) == 0) s[w] = v;
  __syncthreads();
  float r = s[0] + s[1] + s[2] + s[3];
  __syncthreads();
  return r;
}

// ---------------- embed gather + concat + LN0 ----------------
__global__ __launch_bounds__(256) void embed_ln0_k(
    const int* __restrict__ x, const int* __restrict__ qid,
    const float* __restrict__ emb, const float* __restrict__ qc,
    const float* __restrict__ g, const float* __restrict__ bta,
    float* __restrict__ item, unsigned short* __restrict__ item_bf)
{
  __shared__ float sbuf[4];
  int i = blockIdx.x;          // row (b*L + l)
  int t = threadIdx.x;         // 0..255, handles cols 4t..4t+3
  float4 v;
  if (t < 64) v = *(const float4*)&emb[(size_t)x[i] * 256 + t * 4];
  else        v = *(const float4*)&qc[(size_t)qid[i] * 768 + t * 4 - 256];
  float tot = blk_sum(v.x + v.y + v.z + v.w, sbuf);
  float mean = tot * (1.f / 1024.f);
  float dx = v.x - mean, dy = v.y - mean, dz = v.z - mean, dw = v.w - mean;
  float var = blk_sum(dx*dx + dy*dy + dz*dz + dw*dw, sbuf) * (1.f / 1024.f);
  float rstd = rsqrtf(var + 1e-12f);
  float vals[4] = {dx, dy, dz, dw};
  size_t rb = (size_t)i * 1024;
  #pragma unroll
  for (int j = 0; j < 4; j++) {
    int c = t * 4 + j;
    float o = vals[j] * rstd * g[c] + bta[c];
    item[rb + c] = o;
    item_bf[rb + c] = f2bf(o);
  }
}

// ---------------- 128x128 bf16 GEMM (4 waves) — small/odd shapes ----------------
// C[M,N] = A[M,K] * B[N,K]^T.
// EPI 0: f32 store; EPI 1: sigmoid(acc+bias); EPI 2: softplus(acc+bias);
// EPI 3: f32 store + bf16 aux store for col<64 (dt slice).
template <int EPI>
__global__ __launch_bounds__(256) void gemm_bt_k(
    const unsigned short* __restrict__ A, const unsigned short* __restrict__ Bw,
    float* __restrict__ C, const float* __restrict__ bias,
    unsigned short* __restrict__ aux,
    int M, int N, int K)
{
  __shared__ __align__(16) unsigned short As[128 * 64];
  __shared__ __align__(16) unsigned short Bs[128 * 64];
  const int tid = threadIdx.x;
  const int m0 = blockIdx.x * 128;
  const int n0 = blockIdx.y * 128;
  const int w = tid >> 6, lane = tid & 63;
  const int wrow = (w >> 1) * 64, wcol = (w & 1) * 64;
  const int quad = lane >> 4, lid = lane & 15;

  const int srow = lane >> 3;                  // 0..7
  const int schunk = (lane & 7) ^ srow;        // swizzled k-chunk for this lane

  const unsigned short* Abase = A + (size_t)(m0 + w * 8 + srow) * K + schunk * 8;
  const unsigned short* Bbase[4];
  #pragma unroll
  for (int i = 0; i < 4; i++) {
    int rB = n0 + w * 8 + i * 32 + srow;
    if (rB > N - 1) rB = N - 1;
    Bbase[i] = Bw + (size_t)rB * K + schunk * 8;
  }

  f32x4 acc[4][4] = {};

  for (int k0 = 0; k0 < K; k0 += 64) {
    #pragma unroll
    for (int i = 0; i < 4; i++) {
      int rA = w * 8 + i * 32;   // wave-uniform LDS row-group base
      __builtin_amdgcn_global_load_lds(
          (const AS1 unsigned int*)(Abase + (size_t)i * 32 * K + k0),
          (AS3 unsigned int*)&As[rA * 64], 16, 0, 0);
      __builtin_amdgcn_global_load_lds(
          (const AS1 unsigned int*)(Bbase[i] + k0),
          (AS3 unsigned int*)&Bs[rA * 64], 16, 0, 0);
    }
    __syncthreads();
    #pragma unroll
    for (int kk = 0; kk < 64; kk += 32) {
      bf16x8 af[4], bfr[4];
      #pragma unroll
      for (int mi = 0; mi < 4; mi++) {
        int r = wrow + mi * 16 + lid;
        int slot = ((kk >> 3) + quad) ^ (lid & 7);
        af[mi] = *(const bf16x8*)&As[r * 64 + slot * 8];
      }
      #pragma unroll
      for (int ni = 0; ni < 4; ni++) {
        int r = wcol + ni * 16 + lid;
        int slot = ((kk >> 3) + quad) ^ (lid & 7);
        bfr[ni] = *(const bf16x8*)&Bs[r * 64 + slot * 8];
      }
      #pragma unroll
      for (int mi = 0; mi < 4; mi++)
        #pragma unroll
        for (int ni = 0; ni < 4; ni++)
          acc[mi][ni] = __builtin_amdgcn_mfma_f32_16x16x32_bf16(af[mi], bfr[ni], acc[mi][ni], 0, 0, 0);
    }
    __syncthreads();
  }

  #pragma unroll
  for (int mi = 0; mi < 4; mi++) {
    #pragma unroll
    for (int ni = 0; ni < 4; ni++) {
      int col = n0 + wcol + ni * 16 + lid;
      if (col >= N) continue;
      #pragma unroll
      for (int r = 0; r < 4; r++) {
        int row = m0 + wrow + mi * 16 + quad * 4 + r;
        float v = acc[mi][ni][r];
        if (EPI == 1) v = sigmoidf_(v + bias[col]);
        if (EPI == 2) { float xx = v + bias[col]; v = fmaxf(xx, 0.f) + log1pf(expf(-fabsf(xx))); }
        C[(size_t)row * N + col] = v;
        if (EPI == 3 && col < 64) aux[(size_t)row * 64 + col] = f2bf(v);
      }
    }
  }
}

// ---------------- 256xBN bf16 GEMM — 8-phase / counted-vmcnt (m201-style) ----------------
// BM=256, BK=64 as two 32-wide k-slices. 8 waves (2M x 4N), wave tile 128 x BN/4.
// Staging unit = one k-slice of one operand (A: 256x32 = 2 loads/thread;
// B: BN x 32 = BJ loads/thread). Unit stream order: [Ak0,Bk0,Ak1,Bk1] per tile.
// Per K-tile: 4 phases, each = {stage 1 unit of 3-ahead stream; ds_read subtile;
// setprio(1) 16*NB/4 MFMA setprio(0); lgkmcnt(0) when reads pending; s_barrier}.
// vmcnt(4+BJ) ONCE per tile (phase 3) leaves the 3 newest units in flight while
// guaranteeing tile T+1 fully landed — loads span 4 barriers, never drain to 0
// in the steady loop (T3+T4). Race-freedom: every k-slice's reads are lgkm-
// drained + barrier'd one phase before any overwrite of it is issued.
// LDS layout: slice = [rows][4 chunks of 8 bf16], slot = chunk ^ ((row>>1)&3)
// (measured 0 bank conflicts); realized by inverse-swizzled per-lane GLOBAL
// source with linear wave-uniform global_load_lds dest.
template <int BN, int EPI>
__global__ __launch_bounds__(512, 2) void gemm8p_k(
    const unsigned short* __restrict__ A, const unsigned short* __restrict__ Bw,
    float* __restrict__ C, const float* __restrict__ bias,
    int M, int N, int K)
{
  constexpr int NB = BN / 64;        // B frags / MFMA-cols per wave: 4 or 2
  constexpr int BJ = BN / 128;       // B loads per unit per thread: 2 or 1
  constexpr int ASLICE = 256 * 32;
  constexpr int BSLICE = BN * 32;

  __shared__ __align__(16) unsigned short As[4 * ASLICE];   // [buf][ks]
  __shared__ __align__(16) unsigned short Bs[4 * BSLICE];

  const int tid = threadIdx.x;
  const int gx = gridDim.x;
  const int nwg = gx * gridDim.y;
  int bid = blockIdx.y * gx + blockIdx.x;
  bid = (bid & 7) * (nwg >> 3) + (bid >> 3);   // XCD swizzle (nwg % 8 == 0)
  const int m0 = (bid % gx) * 256;
  const int n0 = (bid / gx) * BN;

  const int w = tid >> 6, lane = tid & 63;
  const int wm = w >> 2, wn = w & 3;
  const int quad = lane >> 4, lid = lane & 15;

  // --- staging geometry: 4 lanes cover one 64B row segment (chunks permuted) ---
  const int g8 = ((lane & 3) ^ ((lane >> 3) & 3)) * 8;   // inv-swizzled k-chunk
  const unsigned short* Ag[2];
  int AsegE[2];
  #pragma unroll
  for (int j = 0; j < 2; j++) {
    Ag[j] = A + (size_t)(m0 + w * 32 + j * 16 + (lane >> 2)) * K + g8;
    AsegE[j] = (w * 2 + j) * 512;                        // wave-uniform elem base
  }
  const unsigned short* Bg[BJ];
  int BsegE[BJ];
  #pragma unroll
  for (int j = 0; j < BJ; j++) {
    int rB = n0 + (w * BJ + j) * 16 + (lane >> 2);
    if (rB > N - 1) rB = N - 1;
    Bg[j] = Bw + (size_t)rB * K + g8;
    BsegE[j] = (w * BJ + j) * 512;
  }

  const int NT = K >> 6;
  auto stage_unit = [&](int u) {
    if (u >= 4 * NT) return;
    const int tu = u >> 2, ty = u & 3;
    const int sl = (tu & 1) * 2 + (ty >> 1);             // [buf][ks] slice index
    const size_t kofs = (size_t)(tu << 6) + ((ty >> 1) << 5);
    if ((ty & 1) == 0) {
      #pragma unroll
      for (int j = 0; j < 2; j++)
        __builtin_amdgcn_global_load_lds(
            (const AS1 unsigned int*)(Ag[j] + kofs),
            (AS3 unsigned int*)&As[sl * ASLICE + AsegE[j]], 16, 0, 0);
    } else {
      #pragma unroll
      for (int j = 0; j < BJ; j++)
        __builtin_amdgcn_global_load_lds(
            (const AS1 unsigned int*)(Bg[j] + kofs),
            (AS3 unsigned int*)&Bs[sl * BSLICE + BsegE[j]], 16, 0, 0);
    }
  };

  // --- fragment read offsets (elements within a slice) ---
  const int slot8 = (quad ^ ((lid >> 1) & 3)) * 8;
  const int aoff = (wm * 128 + lid) * 32 + slot8;        // + mi*512
  const int boff = (wn * (BN / 4) + lid) * 32 + slot8;   // + ni*512

  f32x4 acc[8][NB] = {};

  // prologue: units 0..6 (tile0 + tile1's first 3); wait leaves 3 newest in flight
  #pragma unroll
  for (int u = 0; u < 7; u++) stage_unit(u);
  if constexpr (BJ == 2) VMCNT(6); else VMCNT(5);
  SBARRIER();

  for (int T = 0; T < NT; ++T) {
    const int ab = (T & 1) * 2;
    const unsigned short* Asl0 = &As[(ab + 0) * ASLICE];
    const unsigned short* Asl1 = &As[(ab + 1) * ASLICE];
    const unsigned short* Bsl0 = &Bs[(ab + 0) * BSLICE];
    const unsigned short* Bsl1 = &Bs[(ab + 1) * BSLICE];

    bf16x8 af[8], bfr[NB];

    // ---- P0: stage (T+1).Bk1 | read all ks0 frags | MFMA mi0-3 ks0 ----
    stage_unit(4 * T + 7);
    __builtin_amdgcn_sched_barrier(0);
    #pragma unroll
    for (int ni = 0; ni < NB; ni++) bfr[ni] = *(const bf16x8*)&Bsl0[boff + ni * 512];
    #pragma unroll
    for (int mi = 0; mi < 8; mi++)  af[mi]  = *(const bf16x8*)&Asl0[aoff + mi * 512];
    __builtin_amdgcn_s_setprio(1);
    #pragma unroll
    for (int mi = 0; mi < 4; mi++)
      #pragma unroll
      for (int ni = 0; ni < NB; ni++)
        acc[mi][ni] = __builtin_amdgcn_mfma_f32_16x16x32_bf16(af[mi], bfr[ni], acc[mi][ni], 0, 0, 0);
    __builtin_amdgcn_s_setprio(0);
    LGKMCNT0();                          // all ks0 reads done before Ak0/Bk0 overwrite
    __builtin_amdgcn_sched_barrier(0);
    SBARRIER();

    // ---- P1: stage (T+2).Ak0 | MFMA mi4-7 ks0 (regs) ----
    stage_unit(4 * T + 8);
    __builtin_amdgcn_sched_barrier(0);
    __builtin_amdgcn_s_setprio(1);
    #pragma unroll
    for (int mi = 4; mi < 8; mi++)
      #pragma unroll
      for (int ni = 0; ni < NB; ni++)
        acc[mi][ni] = __builtin_amdgcn_mfma_f32_16x16x32_bf16(af[mi], bfr[ni], acc[mi][ni], 0, 0, 0);
    __builtin_amdgcn_s_setprio(0);
    SBARRIER();

    // ---- P2: stage (T+2).Bk0 | read all ks1 frags | MFMA mi0-3 ks1 ----
    stage_unit(4 * T + 9);
    __builtin_amdgcn_sched_barrier(0);
    #pragma unroll
    for (int ni = 0; ni < NB; ni++) bfr[ni] = *(const bf16x8*)&Bsl1[boff + ni * 512];
    #pragma unroll
    for (int mi = 0; mi < 8; mi++)  af[mi]  = *(const bf16x8*)&Asl1[aoff + mi * 512];
    __builtin_amdgcn_s_setprio(1);
    #pragma unroll
    for (int mi = 0; mi < 4; mi++)
      #pragma unroll
      for (int ni = 0; ni < NB; ni++)
        acc[mi][ni] = __builtin_amdgcn_mfma_f32_16x16x32_bf16(af[mi], bfr[ni], acc[mi][ni], 0, 0, 0);
    __builtin_amdgcn_s_setprio(0);
    LGKMCNT0();                          // all ks1 reads done before Ak1 overwrite
    __builtin_amdgcn_sched_barrier(0);
    SBARRIER();

    // ---- P3: stage (T+2).Ak1 | MFMA mi4-7 ks1 | counted vmcnt | barrier ----
    stage_unit(4 * T + 10);
    __builtin_amdgcn_sched_barrier(0);
    __builtin_amdgcn_s_setprio(1);
    #pragma unroll
    for (int mi = 4; mi < 8; mi++)
      #pragma unroll
      for (int ni = 0; ni < NB; ni++)
        acc[mi][ni] = __builtin_amdgcn_mfma_f32_16x16x32_bf16(af[mi], bfr[ni], acc[mi][ni], 0, 0, 0);
    __builtin_amdgcn_s_setprio(0);
    if (T >= NT - 2) { VMCNT(0); }
    else { if constexpr (BJ == 2) VMCNT(6); else VMCNT(5); }
    SBARRIER();
  }

  #pragma unroll
  for (int mi = 0; mi < 8; mi++) {
    #pragma unroll
    for (int ni = 0; ni < NB; ni++) {
      int col = n0 + wn * (BN / 4) + ni * 16 + lid;
      if (col >= N) continue;
      #pragma unroll
      for (int r = 0; r < 4; r++) {
        int row = m0 + wm * 128 + mi * 16 + quad * 4 + r;
        float v = acc[mi][ni][r];
        if (EPI == 1) v = sigmoidf_(v + bias[col]);
        C[(size_t)row * N + col] = v;
      }
    }
  }
}

// ---------------- causal depthwise conv (K=4) + SiLU ----------------
__global__ void conv_silu_k(const float* __restrict__ u_r, const float* __restrict__ w,
                            const float* __restrict__ cb, float* __restrict__ uc,
                            unsigned short* __restrict__ uc_bf)
{
  int idx = blockIdx.x * blockDim.x + threadIdx.x;  // over B*L*DI
  if (idx >= BATCH * L_SEQ * DINNER) return;
  int d = idx & (DINNER - 1);
  int l = (idx >> 11) & (L_SEQ - 1);
  int b = idx >> 21;
  float4 wv = ((const float4*)w)[d];   // w[d][0..3]
  size_t rb = ((size_t)b * L_SEQ + l) * (2 * DINNER) + d;
  float acc = cb[d];
  acc += wv.w * u_r[rb];
  if (l >= 1) acc += wv.z * u_r[rb - (2 * DINNER)];
  if (l >= 2) acc += wv.y * u_r[rb - 2 * (2 * DINNER)];
  if (l >= 3) acc += wv.x * u_r[rb - 3 * (2 * DINNER)];
  float s = acc * sigmoidf_(acc);
  uc[idx] = s;
  uc_bf[idx] = f2bf(s);
}

// ---------------- A2 precompute: a2t[n][d] = -exp(A_log[d][n]) * log2(e) ----------------
__global__ void a2_k(const float* __restrict__ Alog, float* __restrict__ a2t)
{
  int i = blockIdx.x * blockDim.x + threadIdx.x;   // over 2048*16
  if (i >= DINNER * NSTATE) return;
  int d = i >> 4, n = i & 15;
  a2t[n * DINNER + d] = -expf(Alog[i]) * 1.4426950408889634f;
}

// ---------------- chunked scan pass 1: per-chunk aggregates (P, q) with h0=0 ----------------
__global__ __launch_bounds__(64) void scan1_k(
    const float* __restrict__ dlt, const float* __restrict__ uc,
    const float* __restrict__ dbl, const float* __restrict__ a2t,
    float* __restrict__ Pbuf, float* __restrict__ Qbuf)
{
  int c = blockIdx.x;            // chunk
  int dg = blockIdx.y;           // d-group of 64
  int b = blockIdx.z;
  int d = dg * 64 + threadIdx.x;
  float a2[NSTATE], P[NSTATE], q[NSTATE];
  #pragma unroll
  for (int n = 0; n < NSTATE; n++) {
    a2[n] = a2t[n * DINNER + d];
    P[n] = 1.f; q[n] = 0.f;
  }
  size_t base = ((size_t)(b * L_SEQ + c * CH)) * DINNER + d;
  const float* bc = dbl + (size_t)(b * L_SEQ + c * CH) * 96 + 64;
  for (int t = 0; t < CH; t++) {
    float dl = dlt[base];
    float du = dl * uc[base];
    #pragma unroll
    for (int n = 0; n < NSTATE; n++) {
      float dA = exp2f(dl * a2[n]);
      q[n] = dA * q[n] + du * bc[n];
      P[n] *= dA;
    }
    base += DINNER;
    bc += 96;
  }
  size_t ob = ((size_t)((b * NCH + c) * NSTATE)) * DINNER + d;
  #pragma unroll
  for (int n = 0; n < NSTATE; n++) {
    Pbuf[ob + (size_t)n * DINNER] = P[n];
    Qbuf[ob + (size_t)n * DINNER] = q[n];
  }
}

// ---------------- chunked scan carry: sequential combine over chunks ----------------
__global__ void scan_carry_k(const float* __restrict__ Pbuf, float* __restrict__ Qbuf)
{
  int idx = blockIdx.x * blockDim.x + threadIdx.x;  // over 8*16*2048 = 262144
  if (idx >= BATCH * NSTATE * DINNER) return;
  int d = idx & (DINNER - 1);
  int n = (idx >> 11) & 15;
  int b = idx >> 15;
  float h = 0.f;
  for (int c = 0; c < NCH; c++) {
    size_t o = ((size_t)((b * NCH + c) * NSTATE + n)) * DINNER + d;
    float P = Pbuf[o];
    float q = Qbuf[o];
    Qbuf[o] = h;
    h = P * h + q;
  }
}

// ---------------- chunked scan pass 2 + gate fused ----------------
__global__ __launch_bounds__(64) void scan2_k(
    const float* __restrict__ dlt, const float* __restrict__ uc,
    const float* __restrict__ dbl, const float* __restrict__ a2t,
    const float* __restrict__ Qbuf, const float* __restrict__ u_r,
    const float* __restrict__ Dp, unsigned short* __restrict__ ybf)
{
  int c = blockIdx.x;
  int dg = blockIdx.y;
  int b = blockIdx.z;
  int d = dg * 64 + threadIdx.x;
  float a2[NSTATE], h[NSTATE];
  size_t ob = ((size_t)((b * NCH + c) * NSTATE)) * DINNER + d;
  #pragma unroll
  for (int n = 0; n < NSTATE; n++) {
    a2[n] = a2t[n * DINNER + d];
    h[n] = Qbuf[ob + (size_t)n * DINNER];
  }
  float Dd = Dp[d];
  size_t base = ((size_t)(b * L_SEQ + c * CH)) * DINNER + d;
  const float* bc = dbl + (size_t)(b * L_SEQ + c * CH) * 96 + 64;
  const float* rp = u_r + (size_t)(b * L_SEQ + c * CH) * (2 * DINNER) + DINNER + d;
  for (int t = 0; t < CH; t++) {
    float dl = dlt[base];
    float uval = uc[base];
    float du = dl * uval;
    float yv = 0.f;
    #pragma unroll
    for (int n = 0; n < NSTATE; n++) {
      float dA = exp2f(dl * a2[n]);
      h[n] = dA * h[n] + du * bc[n];
      yv += h[n] * bc[NSTATE + n];
    }
    float rv = *rp;
    float val = (yv + uval * Dd) * (rv * sigmoidf_(rv));
    ybf[base] = f2bf(val);
    base += DINNER;
    bc += 96;
    rp += 2 * DINNER;
  }
}

// ---------------- residual + LN1 -> bf16 ----------------
__global__ __launch_bounds__(256) void ln1_k(
    const float* __restrict__ mamba, const float* __restrict__ item,
    const float* __restrict__ g, const float* __restrict__ bta,
    unsigned short* __restrict__ out_bf)
{
  __shared__ float sbuf[4];
  int i = blockIdx.x;
  int t = threadIdx.x;
  size_t rb = (size_t)i * 1024 + t * 4;
  float4 v = *(const float4*)&mamba[rb];
  float4 w4 = *(const float4*)&item[rb];
  v.x += w4.x; v.y += w4.y; v.z += w4.z; v.w += w4.w;
  float tot = blk_sum(v.x + v.y + v.z + v.w, sbuf);
  float mean = tot * (1.f / 1024.f);
  float dx = v.x - mean, dy = v.y - mean, dz = v.z - mean, dw = v.w - mean;
  float var = blk_sum(dx*dx + dy*dy + dz*dz + dw*dw, sbuf) * (1.f / 1024.f);
  float rstd = rsqrtf(var + 1e-12f);
  float vals[4] = {dx, dy, dz, dw};
  #pragma unroll
  for (int j = 0; j < 4; j++) {
    int c = t * 4 + j;
    out_bf[(size_t)i * 1024 + c] = f2bf(vals[j] * rstd * g[c] + bta[c]);
  }
}

// ---------------- launch ----------------
extern "C" void kernel_launch(void* const* d_in, const int* in_sizes, int n_in,
                              void* d_out, int out_size, void* d_ws, size_t ws_size,
                              hipStream_t stream)
{
  (void)in_sizes; (void)n_in; (void)out_size; (void)ws_size;
  const int*   x     = (const int*)d_in[0];
  const int*   qid   = (const int*)d_in[1];
  const float* emb   = (const float*)d_in[2];
  const float* qc    = (const float*)d_in[3];
  const float* ln0g  = (const float*)d_in[4];
  const float* ln0b  = (const float*)d_in[5];
  const float* w_in  = (const float*)d_in[6];
  const float* convw = (const float*)d_in[7];
  const float* convb = (const float*)d_in[8];
  const float* w_x   = (const float*)d_in[9];
  const float* w_dt  = (const float*)d_in[10];
  const float* dtb   = (const float*)d_in[11];
  const float* Alog  = (const float*)d_in[12];
  const float* Dp    = (const float*)d_in[13];
  const float* w_out = (const float*)d_in[14];
  const float* ln1g  = (const float*)d_in[15];
  const float* ln1b  = (const float*)d_in[16];
  const float* w_fc  = (const float*)d_in[17];
  const float* fcb   = (const float*)d_in[18];
  float* out = (float*)d_out;

  char* base = (char*)d_ws;
  size_t off = 0;
  auto carve = [&](size_t bytes) -> char* {
    char* p = base + off;
    off = (off + bytes + 255) & ~(size_t)255;
    return p;
  };
  float* item  = (float*)carve((size_t)NROWS * 1024 * 4);
  float* u_r   = (float*)carve((size_t)NROWS * 4096 * 4);
  float* uc    = (float*)carve((size_t)NROWS * 2048 * 4);
  float* dbl   = (float*)carve((size_t)NROWS * 96 * 4);
  float* dlt   = (float*)carve((size_t)NROWS * 2048 * 4);
  float* mamba = (float*)carve((size_t)NROWS * 1024 * 4);
  unsigned short* bfbuf  = (unsigned short*)carve((size_t)NROWS * 2048 * 2);
  unsigned short* bw_in  = (unsigned short*)carve((size_t)4096 * 1024 * 2);
  unsigned short* bw_x   = (unsigned short*)carve((size_t)96 * 2048 * 2);
  unsigned short* bw_dt  = (unsigned short*)carve((size_t)2048 * 64 * 2);
  unsigned short* bw_out = (unsigned short*)carve((size_t)1024 * 2048 * 2);
  unsigned short* bw_fc  = (unsigned short*)carve((size_t)4000 * 1024 * 2);
  float* a2t   = (float*)carve((size_t)DINNER * NSTATE * 4);

  // Aliasing plan (all hazards separated by stream ordering):
  //   dt_bf  <- (u16*)mamba   written by x_proj epi, read by dt_proj, dead after
  //   Pbuf   <- mamba         scan1 writes (over dead dt_bf), carry reads, dead
  //   Qbuf   <- (f32*)bfbuf   scan1 writes, carry rewrites, scan2 reads, dead
  //   y_bf   <- (u16*)mamba   scan2 writes (over dead Pbuf), out_proj A
  //   mamba_out <- u_r        out_proj C (u_r fully dead after scan2)
  //   ln_bf  <- bfbuf         ln1 writes (over dead Qbuf), fc A
  unsigned short* dt_bf = (unsigned short*)mamba;
  float* Pbuf = mamba;
  float* Qbuf = (float*)bfbuf;
  unsigned short* y_bf = (unsigned short*)mamba;
  float* mamba_out = u_r;

  auto cv = [&](const float* s, unsigned short* dst, int n) {
    cast_bf16_k<<<(n + 255) / 256, 256, 0, stream>>>(s, dst, n);
  };
  cv(w_in,  bw_in,  4096 * 1024);
  cv(w_x,   bw_x,   96 * 2048);
  cv(w_dt,  bw_dt,  2048 * 64);
  cv(w_out, bw_out, 1024 * 2048);
  cv(w_fc,  bw_fc,  4000 * 1024);
  a2_k<<<(DINNER * NSTATE + 255) / 256, 256, 0, stream>>>(Alog, a2t);

  // 1. embedding gather + concat + LN0
  embed_ln0_k<<<NROWS, 256, 0, stream>>>(x, qid, emb, qc, ln0g, ln0b, item, bfbuf);

  // 2. in_proj: (8192,1024) x (4096,1024)^T -> u_r   [8-phase 256x256]
  gemm8p_k<256, 0><<<dim3(32, 16), 512, 0, stream>>>(bfbuf, bw_in, u_r, nullptr, NROWS, 4096, 1024);

  // 3. conv + silu
  conv_silu_k<<<(NROWS * DINNER) / 256, 256, 0, stream>>>(u_r, convw, convb, uc, bfbuf);

  // 4. x_proj: (8192,2048) x (96,2048)^T -> dbl, + dt slice -> bf16 (fused)
  gemm_bt_k<3><<<dim3(64, 1), 256, 0, stream>>>(bfbuf, bw_x, dbl, nullptr, dt_bf, NROWS, 96, 2048);

  // 5. dt_proj: (8192,64) x (2048,64)^T -> softplus(acc + dt_bias) -> dlt (fused)
  gemm_bt_k<2><<<dim3(64, 16), 256, 0, stream>>>(dt_bf, bw_dt, dlt, dtb, nullptr, NROWS, 2048, 64);

  // 6. chunked selective scan
  scan1_k<<<dim3(NCH, 32, BATCH), 64, 0, stream>>>(dlt, uc, dbl, a2t, Pbuf, Qbuf);
  scan_carry_k<<<(BATCH * NSTATE * DINNER) / 256, 256, 0, stream>>>(Pbuf, Qbuf);
  // 7. scan pass 2 + gate fused -> y_bf
  scan2_k<<<dim3(NCH, 32, BATCH), 64, 0, stream>>>(dlt, uc, dbl, a2t, Qbuf, u_r, Dp, y_bf);

  // 8. out_proj: (8192,2048) x (1024,2048)^T -> mamba_out   [8-phase 256x128]
  gemm8p_k<128, 0><<<dim3(32, 8), 512, 0, stream>>>(y_bf, bw_out, mamba_out, nullptr, NROWS, 1024, 2048);

  // 9. residual + LN1 -> bf16
  ln1_k<<<NROWS, 256, 0, stream>>>(mamba_out, item, ln1g, ln1b, bfbuf);

  // 10. fc + sigmoid -> out   [8-phase 256x256]
  gemm8p_k<256, 1><<<dim3(32, 16), 512, 0, stream>>>(bfbuf, bw_fc, out, fcb, NROWS, 4000, 1024);
}

// Round 4
// 855.330 us; speedup vs baseline: 1.2791x; 1.2791x over previous
//
#include <hip/hip_runtime.h>
#include <cstdint>
#include <cstddef>

#define L_SEQ 1024
#define BATCH 8
#define DMODEL 1024
#define DINNER 2048
#define NSTATE 16
#define DTRANK 64
#define NQ 4000
#define NROWS (BATCH * L_SEQ)   // 8192
#define CH 64                   // scan chunk length
#define NCH (L_SEQ / CH)        // 16 chunks
#define XKN 96                  // x_proj output cols

typedef float f32x4 __attribute__((ext_vector_type(4)));
typedef __bf16 bf16x8 __attribute__((ext_vector_type(8)));

#define AS1 __attribute__((address_space(1)))
#define AS3 __attribute__((address_space(3)))

__device__ __forceinline__ unsigned short f2bf(float f) {
  union { float f; unsigned int u; } c; c.f = f;
  unsigned int u = c.u;
  unsigned int r = u + 0x7fffu + ((u >> 16) & 1u);
  return (unsigned short)(r >> 16);
}

__device__ __forceinline__ float sigmoidf_(float x) { return 1.f / (1.f + expf(-x)); }

// ---------------- weight fp32 -> bf16 cast ----------------
__global__ void cast_bf16_k(const float* __restrict__ src, unsigned short* __restrict__ dst, int n) {
  int i = blockIdx.x * blockDim.x + threadIdx.x;
  if (i < n) dst[i] = f2bf(src[i]);
}

// ---------------- block reduction helper (256 threads, 4 waves) ----------------
__device__ __forceinline__ float blk_sum(float v, float* s) {
  #pragma unroll
  for (int o = 32; o > 0; o >>= 1) v += __shfl_down(v, o, 64);
  int w = threadIdx.x >> 6;
  if ((threadIdx.x & 63) == 0) s[w] = v;
  __syncthreads();
  float r = s[0] + s[1] + s[2] + s[3];
  __syncthreads();
  return r;
}

// ---------------- embed gather + concat + LN0 ----------------
__global__ __launch_bounds__(256) void embed_ln0_k(
    const int* __restrict__ x, const int* __restrict__ qid,
    const float* __restrict__ emb, const float* __restrict__ qc,
    const float* __restrict__ g, const float* __restrict__ bta,
    float* __restrict__ item, unsigned short* __restrict__ item_bf)
{
  __shared__ float sbuf[4];
  int i = blockIdx.x;          // row (b*L + l)
  int t = threadIdx.x;         // 0..255, handles cols 4t..4t+3
  float4 v;
  if (t < 64) v = *(const float4*)&emb[(size_t)x[i] * 256 + t * 4];
  else        v = *(const float4*)&qc[(size_t)qid[i] * 768 + t * 4 - 256];
  float tot = blk_sum(v.x + v.y + v.z + v.w, sbuf);
  float mean = tot * (1.f / 1024.f);
  float dx = v.x - mean, dy = v.y - mean, dz = v.z - mean, dw = v.w - mean;
  float var = blk_sum(dx*dx + dy*dy + dz*dz + dw*dw, sbuf) * (1.f / 1024.f);
  float rstd = rsqrtf(var + 1e-12f);
  float vals[4] = {dx, dy, dz, dw};
  size_t rb = (size_t)i * 1024;
  #pragma unroll
  for (int j = 0; j < 4; j++) {
    int c = t * 4 + j;
    float o = vals[j] * rstd * g[c] + bta[c];
    item[rb + c] = o;
    item_bf[rb + c] = f2bf(o);
  }
}

// ---------------- 128x128 bf16 GEMM via global_load_lds + XOR-swizzled LDS ----------------
// C[M,N] = A[M,K] * B[N,K]^T.  (proven 122 us @ in_proj/fc shapes, 0 bank conflicts)
// EPI 0: f32 store; EPI 1: sigmoid(acc+bias); EPI 2: softplus(acc+bias).
template <int EPI>
__global__ __launch_bounds__(256) void gemm_bt_k(
    const unsigned short* __restrict__ A, const unsigned short* __restrict__ Bw,
    float* __restrict__ C, const float* __restrict__ bias,
    int M, int N, int K)
{
  __shared__ __align__(16) unsigned short As[128 * 64];
  __shared__ __align__(16) unsigned short Bs[128 * 64];
  const int tid = threadIdx.x;
  const int m0 = blockIdx.x * 128;
  const int n0 = blockIdx.y * 128;
  const int w = tid >> 6, lane = tid & 63;
  const int wrow = (w >> 1) * 64, wcol = (w & 1) * 64;
  const int quad = lane >> 4, lid = lane & 15;

  const int srow = lane >> 3;                  // 0..7
  const int schunk = (lane & 7) ^ srow;        // swizzled k-chunk for this lane

  const unsigned short* Abase = A + (size_t)(m0 + w * 8 + srow) * K + schunk * 8;
  const unsigned short* Bbase[4];
  #pragma unroll
  for (int i = 0; i < 4; i++) {
    int rB = n0 + w * 8 + i * 32 + srow;
    if (rB > N - 1) rB = N - 1;
    Bbase[i] = Bw + (size_t)rB * K + schunk * 8;
  }

  f32x4 acc[4][4] = {};

  for (int k0 = 0; k0 < K; k0 += 64) {
    #pragma unroll
    for (int i = 0; i < 4; i++) {
      int rA = w * 8 + i * 32;   // wave-uniform LDS row-group base
      __builtin_amdgcn_global_load_lds(
          (const AS1 unsigned int*)(Abase + (size_t)i * 32 * K + k0),
          (AS3 unsigned int*)&As[rA * 64], 16, 0, 0);
      __builtin_amdgcn_global_load_lds(
          (const AS1 unsigned int*)(Bbase[i] + k0),
          (AS3 unsigned int*)&Bs[rA * 64], 16, 0, 0);
    }
    __syncthreads();
    #pragma unroll
    for (int kk = 0; kk < 64; kk += 32) {
      bf16x8 af[4], bfr[4];
      #pragma unroll
      for (int mi = 0; mi < 4; mi++) {
        int r = wrow + mi * 16 + lid;
        int slot = ((kk >> 3) + quad) ^ (lid & 7);
        af[mi] = *(const bf16x8*)&As[r * 64 + slot * 8];
      }
      #pragma unroll
      for (int ni = 0; ni < 4; ni++) {
        int r = wcol + ni * 16 + lid;
        int slot = ((kk >> 3) + quad) ^ (lid & 7);
        bfr[ni] = *(const bf16x8*)&Bs[r * 64 + slot * 8];
      }
      #pragma unroll
      for (int mi = 0; mi < 4; mi++)
        #pragma unroll
        for (int ni = 0; ni < 4; ni++)
          acc[mi][ni] = __builtin_amdgcn_mfma_f32_16x16x32_bf16(af[mi], bfr[ni], acc[mi][ni], 0, 0, 0);
    }
    __syncthreads();
  }

  #pragma unroll
  for (int mi = 0; mi < 4; mi++) {
    #pragma unroll
    for (int ni = 0; ni < 4; ni++) {
      int col = n0 + wcol + ni * 16 + lid;
      if (col >= N) continue;
      #pragma unroll
      for (int r = 0; r < 4; r++) {
        int row = m0 + wrow + mi * 16 + quad * 4 + r;
        float v = acc[mi][ni][r];
        if (EPI == 1) v = sigmoidf_(v + bias[col]);
        if (EPI == 2) { float xx = v + bias[col]; v = fmaxf(xx, 0.f) + log1pf(expf(-fabsf(xx))); }
        C[(size_t)row * N + col] = v;
      }
    }
  }
}

// ---------------- x_proj split-K GEMM: (8192,2048) x (96,2048)^T ----------------
// Grid (64 m-blocks, 4 k-slices) = 256 blocks (1/CU) instead of 64 — the
// unsplit version leaves 75% of CUs idle and serializes 32 k-tiles per block.
// Partials go to slab[ks][row][96]; xproj_reduce_k sums them.
__global__ __launch_bounds__(256) void gemm_xk_k(
    const unsigned short* __restrict__ A, const unsigned short* __restrict__ Bw,
    float* __restrict__ slab, int M, int K, int KS)
{
  __shared__ __align__(16) unsigned short As[128 * 64];
  __shared__ __align__(16) unsigned short Bs[128 * 64];
  const int tid = threadIdx.x;
  const int m0 = blockIdx.x * 128;
  const int kslice = blockIdx.y;
  const int w = tid >> 6, lane = tid & 63;
  const int wrow = (w >> 1) * 64, wcol = (w & 1) * 64;
  const int quad = lane >> 4, lid = lane & 15;

  const int srow = lane >> 3;
  const int schunk = (lane & 7) ^ srow;

  const unsigned short* Abase = A + (size_t)(m0 + w * 8 + srow) * K + schunk * 8;
  const unsigned short* Bbase[4];
  #pragma unroll
  for (int i = 0; i < 4; i++) {
    int rB = w * 8 + i * 32 + srow;
    if (rB > XKN - 1) rB = XKN - 1;
    Bbase[i] = Bw + (size_t)rB * K + schunk * 8;
  }

  f32x4 acc[4][4] = {};
  const int kbeg = kslice * KS, kend = kbeg + KS;

  for (int k0 = kbeg; k0 < kend; k0 += 64) {
    #pragma unroll
    for (int i = 0; i < 4; i++) {
      int rA = w * 8 + i * 32;
      __builtin_amdgcn_global_load_lds(
          (const AS1 unsigned int*)(Abase + (size_t)i * 32 * K + k0),
          (AS3 unsigned int*)&As[rA * 64], 16, 0, 0);
      __builtin_amdgcn_global_load_lds(
          (const AS1 unsigned int*)(Bbase[i] + k0),
          (AS3 unsigned int*)&Bs[rA * 64], 16, 0, 0);
    }
    __syncthreads();
    #pragma unroll
    for (int kk = 0; kk < 64; kk += 32) {
      bf16x8 af[4], bfr[4];
      #pragma unroll
      for (int mi = 0; mi < 4; mi++) {
        int r = wrow + mi * 16 + lid;
        int slot = ((kk >> 3) + quad) ^ (lid & 7);
        af[mi] = *(const bf16x8*)&As[r * 64 + slot * 8];
      }
      #pragma unroll
      for (int ni = 0; ni < 4; ni++) {
        int r = wcol + ni * 16 + lid;
        int slot = ((kk >> 3) + quad) ^ (lid & 7);
        bfr[ni] = *(const bf16x8*)&Bs[r * 64 + slot * 8];
      }
      #pragma unroll
      for (int mi = 0; mi < 4; mi++)
        #pragma unroll
        for (int ni = 0; ni < 4; ni++)
          acc[mi][ni] = __builtin_amdgcn_mfma_f32_16x16x32_bf16(af[mi], bfr[ni], acc[mi][ni], 0, 0, 0);
    }
    __syncthreads();
  }

  float* Cs = slab + (size_t)kslice * M * XKN;
  #pragma unroll
  for (int mi = 0; mi < 4; mi++) {
    #pragma unroll
    for (int ni = 0; ni < 4; ni++) {
      int col = wcol + ni * 16 + lid;
      if (col >= XKN) continue;
      #pragma unroll
      for (int r = 0; r < 4; r++) {
        int row = m0 + wrow + mi * 16 + quad * 4 + r;
        Cs[(size_t)row * XKN + col] = acc[mi][ni][r];
      }
    }
  }
}

// ---------------- x_proj reduce: dbl = sum of 4 slabs; dt slice -> bf16 ----------------
__global__ void xproj_reduce_k(const float* __restrict__ slab, float* __restrict__ dbl,
                               unsigned short* __restrict__ dt_bf)
{
  int i = blockIdx.x * blockDim.x + threadIdx.x;   // over 8192*96
  if (i >= NROWS * XKN) return;
  const size_t S = (size_t)NROWS * XKN;
  float s = slab[i] + slab[i + S] + slab[i + 2 * S] + slab[i + 3 * S];
  dbl[i] = s;
  int row = i / XKN, col = i - row * XKN;
  if (col < 64) dt_bf[(size_t)row * 64 + col] = f2bf(s);
}

// ---------------- causal depthwise conv (K=4) + SiLU ----------------
__global__ void conv_silu_k(const float* __restrict__ u_r, const float* __restrict__ w,
                            const float* __restrict__ cb, float* __restrict__ uc,
                            unsigned short* __restrict__ uc_bf)
{
  int idx = blockIdx.x * blockDim.x + threadIdx.x;  // over B*L*DI
  if (idx >= BATCH * L_SEQ * DINNER) return;
  int d = idx & (DINNER - 1);
  int l = (idx >> 11) & (L_SEQ - 1);
  int b = idx >> 21;
  float4 wv = ((const float4*)w)[d];   // w[d][0..3]
  size_t rb = ((size_t)b * L_SEQ + l) * (2 * DINNER) + d;
  float acc = cb[d];
  acc += wv.w * u_r[rb];
  if (l >= 1) acc += wv.z * u_r[rb - (2 * DINNER)];
  if (l >= 2) acc += wv.y * u_r[rb - 2 * (2 * DINNER)];
  if (l >= 3) acc += wv.x * u_r[rb - 3 * (2 * DINNER)];
  float s = acc * sigmoidf_(acc);
  uc[idx] = s;
  uc_bf[idx] = f2bf(s);
}

// ---------------- A2 precompute: a2t[n][d] = -exp(A_log[d][n]) * log2(e) ----------------
__global__ void a2_k(const float* __restrict__ Alog, float* __restrict__ a2t)
{
  int i = blockIdx.x * blockDim.x + threadIdx.x;   // over 2048*16
  if (i >= DINNER * NSTATE) return;
  int d = i >> 4, n = i & 15;
  a2t[n * DINNER + d] = -expf(Alog[i]) * 1.4426950408889634f;
}

// ---------------- chunked scan pass 1: per-chunk aggregates (P, q) with h0=0 ----------------
__global__ __launch_bounds__(64) void scan1_k(
    const float* __restrict__ dlt, const float* __restrict__ uc,
    const float* __restrict__ dbl, const float* __restrict__ a2t,
    float* __restrict__ Pbuf, float* __restrict__ Qbuf)
{
  int c = blockIdx.x;            // chunk
  int dg = blockIdx.y;           // d-group of 64
  int b = blockIdx.z;
  int d = dg * 64 + threadIdx.x;
  float a2[NSTATE], P[NSTATE], q[NSTATE];
  #pragma unroll
  for (int n = 0; n < NSTATE; n++) {
    a2[n] = a2t[n * DINNER + d];
    P[n] = 1.f; q[n] = 0.f;
  }
  size_t base = ((size_t)(b * L_SEQ + c * CH)) * DINNER + d;
  const float* bc = dbl + (size_t)(b * L_SEQ + c * CH) * XKN + 64;
  for (int t = 0; t < CH; t++) {
    float dl = dlt[base];
    float du = dl * uc[base];
    #pragma unroll
    for (int n = 0; n < NSTATE; n++) {
      float dA = exp2f(dl * a2[n]);
      q[n] = dA * q[n] + du * bc[n];
      P[n] *= dA;
    }
    base += DINNER;
    bc += XKN;
  }
  size_t ob = ((size_t)((b * NCH + c) * NSTATE)) * DINNER + d;
  #pragma unroll
  for (int n = 0; n < NSTATE; n++) {
    Pbuf[ob + (size_t)n * DINNER] = P[n];
    Qbuf[ob + (size_t)n * DINNER] = q[n];
  }
}

// ---------------- chunked scan carry: sequential combine over chunks ----------------
__global__ void scan_carry_k(const float* __restrict__ Pbuf, float* __restrict__ Qbuf)
{
  int idx = blockIdx.x * blockDim.x + threadIdx.x;  // over 8*16*2048 = 262144
  if (idx >= BATCH * NSTATE * DINNER) return;
  int d = idx & (DINNER - 1);
  int n = (idx >> 11) & 15;
  int b = idx >> 15;
  float h = 0.f;
  for (int c = 0; c < NCH; c++) {
    size_t o = ((size_t)((b * NCH + c) * NSTATE + n)) * DINNER + d;
    float P = Pbuf[o];
    float q = Qbuf[o];
    Qbuf[o] = h;
    h = P * h + q;
  }
}

// ---------------- chunked scan pass 2 + gate fused ----------------
// Replays with true h_init, then applies (y + u*D) * silu(r) and writes bf16.
__global__ __launch_bounds__(64) void scan2_k(
    const float* __restrict__ dlt, const float* __restrict__ uc,
    const float* __restrict__ dbl, const float* __restrict__ a2t,
    const float* __restrict__ Qbuf, const float* __restrict__ u_r,
    const float* __restrict__ Dp, unsigned short* __restrict__ ybf)
{
  int c = blockIdx.x;
  int dg = blockIdx.y;
  int b = blockIdx.z;
  int d = dg * 64 + threadIdx.x;
  float a2[NSTATE], h[NSTATE];
  size_t ob = ((size_t)((b * NCH + c) * NSTATE)) * DINNER + d;
  #pragma unroll
  for (int n = 0; n < NSTATE; n++) {
    a2[n] = a2t[n * DINNER + d];
    h[n] = Qbuf[ob + (size_t)n * DINNER];
  }
  float Dd = Dp[d];
  size_t base = ((size_t)(b * L_SEQ + c * CH)) * DINNER + d;
  const float* bc = dbl + (size_t)(b * L_SEQ + c * CH) * XKN + 64;
  const float* rp = u_r + (size_t)(b * L_SEQ + c * CH) * (2 * DINNER) + DINNER + d;
  for (int t = 0; t < CH; t++) {
    float dl = dlt[base];
    float uval = uc[base];
    float du = dl * uval;
    float yv = 0.f;
    #pragma unroll
    for (int n = 0; n < NSTATE; n++) {
      float dA = exp2f(dl * a2[n]);
      h[n] = dA * h[n] + du * bc[n];
      yv += h[n] * bc[NSTATE + n];
    }
    float rv = *rp;
    float val = (yv + uval * Dd) * (rv * sigmoidf_(rv));
    ybf[base] = f2bf(val);
    base += DINNER;
    bc += XKN;
    rp += 2 * DINNER;
  }
}

// ---------------- residual + LN1 -> bf16 ----------------
__global__ __launch_bounds__(256) void ln1_k(
    const float* __restrict__ mamba, const float* __restrict__ item,
    const float* __restrict__ g, const float* __restrict__ bta,
    unsigned short* __restrict__ out_bf)
{
  __shared__ float sbuf[4];
  int i = blockIdx.x;
  int t = threadIdx.x;
  size_t rb = (size_t)i * 1024 + t * 4;
  float4 v = *(const float4*)&mamba[rb];
  float4 w4 = *(const float4*)&item[rb];
  v.x += w4.x; v.y += w4.y; v.z += w4.z; v.w += w4.w;
  float tot = blk_sum(v.x + v.y + v.z + v.w, sbuf);
  float mean = tot * (1.f / 1024.f);
  float dx = v.x - mean, dy = v.y - mean, dz = v.z - mean, dw = v.w - mean;
  float var = blk_sum(dx*dx + dy*dy + dz*dz + dw*dw, sbuf) * (1.f / 1024.f);
  float rstd = rsqrtf(var + 1e-12f);
  float vals[4] = {dx, dy, dz, dw};
  #pragma unroll
  for (int j = 0; j < 4; j++) {
    int c = t * 4 + j;
    out_bf[(size_t)i * 1024 + c] = f2bf(vals[j] * rstd * g[c] + bta[c]);
  }
}

// ---------------- launch ----------------
extern "C" void kernel_launch(void* const* d_in, const int* in_sizes, int n_in,
                              void* d_out, int out_size, void* d_ws, size_t ws_size,
                              hipStream_t stream)
{
  (void)in_sizes; (void)n_in; (void)out_size; (void)ws_size;
  const int*   x     = (const int*)d_in[0];
  const int*   qid   = (const int*)d_in[1];
  const float* emb   = (const float*)d_in[2];
  const float* qc    = (const float*)d_in[3];
  const float* ln0g  = (const float*)d_in[4];
  const float* ln0b  = (const float*)d_in[5];
  const float* w_in  = (const float*)d_in[6];
  const float* convw = (const float*)d_in[7];
  const float* convb = (const float*)d_in[8];
  const float* w_x   = (const float*)d_in[9];
  const float* w_dt  = (const float*)d_in[10];
  const float* dtb   = (const float*)d_in[11];
  const float* Alog  = (const float*)d_in[12];
  const float* Dp    = (const float*)d_in[13];
  const float* w_out = (const float*)d_in[14];
  const float* ln1g  = (const float*)d_in[15];
  const float* ln1b  = (const float*)d_in[16];
  const float* w_fc  = (const float*)d_in[17];
  const float* fcb   = (const float*)d_in[18];
  float* out = (float*)d_out;

  char* base = (char*)d_ws;
  size_t off = 0;
  auto carve = [&](size_t bytes) -> char* {
    char* p = base + off;
    off = (off + bytes + 255) & ~(size_t)255;
    return p;
  };
  float* item  = (float*)carve((size_t)NROWS * 1024 * 4);
  float* u_r   = (float*)carve((size_t)NROWS * 4096 * 4);
  float* uc    = (float*)carve((size_t)NROWS * 2048 * 4);
  float* dbl   = (float*)carve((size_t)NROWS * XKN * 4);
  float* dlt   = (float*)carve((size_t)NROWS * 2048 * 4);
  float* mamba = (float*)carve((size_t)NROWS * 1024 * 4);
  unsigned short* bfbuf  = (unsigned short*)carve((size_t)NROWS * 2048 * 2);
  unsigned short* bw_in  = (unsigned short*)carve((size_t)4096 * 1024 * 2);
  unsigned short* bw_x   = (unsigned short*)carve((size_t)XKN * 2048 * 2);
  unsigned short* bw_dt  = (unsigned short*)carve((size_t)2048 * 64 * 2);
  unsigned short* bw_out = (unsigned short*)carve((size_t)1024 * 2048 * 2);
  unsigned short* bw_fc  = (unsigned short*)carve((size_t)4000 * 1024 * 2);
  float* a2t   = (float*)carve((size_t)DINNER * NSTATE * 4);

  // Aliasing plan (all hazards separated by stream ordering):
  //   slab   <- dlt           x_proj partials (12.6 MB), dead after reduce;
  //                           dt_proj then overwrites dlt
  //   dt_bf  <- (u16*)mamba   written by reduce, read by dt_proj, dead after
  //   Pbuf   <- mamba         scan1 writes (over dead dt_bf), carry reads, dead
  //   Qbuf   <- (f32*)bfbuf   scan1 writes, carry rewrites, scan2 reads, dead
  //   y_bf   <- (u16*)mamba   scan2 writes (over dead Pbuf), out_proj A
  //   mamba_out <- u_r        out_proj C (u_r fully dead after scan2)
  //   ln_bf  <- bfbuf         ln1 writes (over dead Qbuf), fc A
  float* slab = dlt;
  unsigned short* dt_bf = (unsigned short*)mamba;
  float* Pbuf = mamba;
  float* Qbuf = (float*)bfbuf;
  unsigned short* y_bf = (unsigned short*)mamba;
  float* mamba_out = u_r;

  auto cv = [&](const float* s, unsigned short* dst, int n) {
    cast_bf16_k<<<(n + 255) / 256, 256, 0, stream>>>(s, dst, n);
  };
  cv(w_in,  bw_in,  4096 * 1024);
  cv(w_x,   bw_x,   XKN * 2048);
  cv(w_dt,  bw_dt,  2048 * 64);
  cv(w_out, bw_out, 1024 * 2048);
  cv(w_fc,  bw_fc,  4000 * 1024);
  a2_k<<<(DINNER * NSTATE + 255) / 256, 256, 0, stream>>>(Alog, a2t);

  // 1. embedding gather + concat + LN0
  embed_ln0_k<<<NROWS, 256, 0, stream>>>(x, qid, emb, qc, ln0g, ln0b, item, bfbuf);

  // 2. in_proj: (8192,1024) x (4096,1024)^T -> u_r
  gemm_bt_k<0><<<dim3(64, 32), 256, 0, stream>>>(bfbuf, bw_in, u_r, nullptr, NROWS, 4096, 1024);

  // 3. conv + silu
  conv_silu_k<<<(NROWS * DINNER) / 256, 256, 0, stream>>>(u_r, convw, convb, uc, bfbuf);

  // 4. x_proj split-K (4 slices, 256 blocks) + reduce (also emits dt bf16 slice)
  gemm_xk_k<<<dim3(64, 4), 256, 0, stream>>>(bfbuf, bw_x, slab, NROWS, 2048, 512);
  xproj_reduce_k<<<(NROWS * XKN) / 256, 256, 0, stream>>>(slab, dbl, dt_bf);

  // 5. dt_proj: (8192,64) x (2048,64)^T -> softplus(acc + dt_bias) -> dlt (fused)
  gemm_bt_k<2><<<dim3(64, 16), 256, 0, stream>>>(dt_bf, bw_dt, dlt, dtb, NROWS, 2048, 64);

  // 6. chunked selective scan (CH=64)
  scan1_k<<<dim3(NCH, 32, BATCH), 64, 0, stream>>>(dlt, uc, dbl, a2t, Pbuf, Qbuf);
  scan_carry_k<<<(BATCH * NSTATE * DINNER) / 256, 256, 0, stream>>>(Pbuf, Qbuf);
  // 7. scan pass 2 + gate fused -> y_bf
  scan2_k<<<dim3(NCH, 32, BATCH), 64, 0, stream>>>(dlt, uc, dbl, a2t, Qbuf, u_r, Dp, y_bf);

  // 8. out_proj: (8192,2048) x (1024,2048)^T -> mamba_out (=u_r region)
  gemm_bt_k<0><<<dim3(64, 8), 256, 0, stream>>>(y_bf, bw_out, mamba_out, nullptr, NROWS, 1024, 2048);

  // 9. residual + LN1 -> bf16
  ln1_k<<<NROWS, 256, 0, stream>>>(mamba_out, item, ln1g, ln1b, bfbuf);

  // 10. fc + sigmoid -> out
  gemm_bt_k<1><<<dim3(64, 32), 256, 0, stream>>>(bfbuf, bw_fc, out, fcb, NROWS, 4000, 1024);
}

// Round 5
// 822.690 us; speedup vs baseline: 1.3299x; 1.0397x over previous
//
#include <hip/hip_runtime.h>
#include <cstdint>
#include <cstddef>

#define L_SEQ 1024
#define BATCH 8
#define DMODEL 1024
#define DINNER 2048
#define NSTATE 16
#define DTRANK 64
#define NQ 4000
#define NROWS (BATCH * L_SEQ)   // 8192
#define CH 64                   // scan chunk length
#define NCH (L_SEQ / CH)        // 16 chunks
#define XKN 96                  // x_proj output cols

typedef float f32x4 __attribute__((ext_vector_type(4)));
typedef __bf16 bf16x8 __attribute__((ext_vector_type(8)));

#define AS1 __attribute__((address_space(1)))
#define AS3 __attribute__((address_space(3)))

__device__ __forceinline__ unsigned short f2bf(float f) {
  union { float f; unsigned int u; } c; c.f = f;
  unsigned int u = c.u;
  unsigned int r = u + 0x7fffu + ((u >> 16) & 1u);
  return (unsigned short)(r >> 16);
}

__device__ __forceinline__ float bf2f(unsigned short h) {
  union { unsigned int u; float f; } c; c.u = (unsigned int)h << 16;
  return c.f;
}

__device__ __forceinline__ float sigmoidf_(float x) { return 1.f / (1.f + expf(-x)); }

// ---------------- weight fp32 -> bf16 cast ----------------
__global__ void cast_bf16_k(const float* __restrict__ src, unsigned short* __restrict__ dst, int n) {
  int i = blockIdx.x * blockDim.x + threadIdx.x;
  if (i < n) dst[i] = f2bf(src[i]);
}

// ---------------- block reduction helper (256 threads, 4 waves) ----------------
__device__ __forceinline__ float blk_sum(float v, float* s) {
  #pragma unroll
  for (int o = 32; o > 0; o >>= 1) v += __shfl_down(v, o, 64);
  int w = threadIdx.x >> 6;
  if ((threadIdx.x & 63) == 0) s[w] = v;
  __syncthreads();
  float r = s[0] + s[1] + s[2] + s[3];
  __syncthreads();
  return r;
}

// ---------------- embed gather + concat + LN0 -> bf16 only ----------------
__global__ __launch_bounds__(256) void embed_ln0_k(
    const int* __restrict__ x, const int* __restrict__ qid,
    const float* __restrict__ emb, const float* __restrict__ qc,
    const float* __restrict__ g, const float* __restrict__ bta,
    unsigned short* __restrict__ item_bf)
{
  __shared__ float sbuf[4];
  int i = blockIdx.x;          // row (b*L + l)
  int t = threadIdx.x;         // 0..255, handles cols 4t..4t+3
  float4 v;
  if (t < 64) v = *(const float4*)&emb[(size_t)x[i] * 256 + t * 4];
  else        v = *(const float4*)&qc[(size_t)qid[i] * 768 + t * 4 - 256];
  float tot = blk_sum(v.x + v.y + v.z + v.w, sbuf);
  float mean = tot * (1.f / 1024.f);
  float dx = v.x - mean, dy = v.y - mean, dz = v.z - mean, dw = v.w - mean;
  float var = blk_sum(dx*dx + dy*dy + dz*dz + dw*dw, sbuf) * (1.f / 1024.f);
  float rstd = rsqrtf(var + 1e-12f);
  float vals[4] = {dx, dy, dz, dw};
  size_t rb = (size_t)i * 1024;
  #pragma unroll
  for (int j = 0; j < 4; j++) {
    int c = t * 4 + j;
    item_bf[rb + c] = f2bf(vals[j] * rstd * g[c] + bta[c]);
  }
}

// ---------------- 128x128 bf16 GEMM via global_load_lds + XOR-swizzled LDS ----------------
// C[M,N] = A[M,K] * B[N,K]^T.  (proven 122 us @ in_proj/fc shapes, 0 bank conflicts)
// EPI 0: f32 store; EPI 1: sigmoid(acc+bias) f32; EPI 2: softplus(acc+bias) f32;
// EPI 4: bf16 store (C reinterpreted as u16).
template <int EPI>
__global__ __launch_bounds__(256) void gemm_bt_k(
    const unsigned short* __restrict__ A, const unsigned short* __restrict__ Bw,
    float* __restrict__ C, const float* __restrict__ bias,
    int M, int N, int K)
{
  __shared__ __align__(16) unsigned short As[128 * 64];
  __shared__ __align__(16) unsigned short Bs[128 * 64];
  const int tid = threadIdx.x;
  const int m0 = blockIdx.x * 128;
  const int n0 = blockIdx.y * 128;
  const int w = tid >> 6, lane = tid & 63;
  const int wrow = (w >> 1) * 64, wcol = (w & 1) * 64;
  const int quad = lane >> 4, lid = lane & 15;

  const int srow = lane >> 3;                  // 0..7
  const int schunk = (lane & 7) ^ srow;        // swizzled k-chunk for this lane

  const unsigned short* Abase = A + (size_t)(m0 + w * 8 + srow) * K + schunk * 8;
  const unsigned short* Bbase[4];
  #pragma unroll
  for (int i = 0; i < 4; i++) {
    int rB = n0 + w * 8 + i * 32 + srow;
    if (rB > N - 1) rB = N - 1;
    Bbase[i] = Bw + (size_t)rB * K + schunk * 8;
  }

  f32x4 acc[4][4] = {};

  for (int k0 = 0; k0 < K; k0 += 64) {
    #pragma unroll
    for (int i = 0; i < 4; i++) {
      int rA = w * 8 + i * 32;   // wave-uniform LDS row-group base
      __builtin_amdgcn_global_load_lds(
          (const AS1 unsigned int*)(Abase + (size_t)i * 32 * K + k0),
          (AS3 unsigned int*)&As[rA * 64], 16, 0, 0);
      __builtin_amdgcn_global_load_lds(
          (const AS1 unsigned int*)(Bbase[i] + k0),
          (AS3 unsigned int*)&Bs[rA * 64], 16, 0, 0);
    }
    __syncthreads();
    #pragma unroll
    for (int kk = 0; kk < 64; kk += 32) {
      bf16x8 af[4], bfr[4];
      #pragma unroll
      for (int mi = 0; mi < 4; mi++) {
        int r = wrow + mi * 16 + lid;
        int slot = ((kk >> 3) + quad) ^ (lid & 7);
        af[mi] = *(const bf16x8*)&As[r * 64 + slot * 8];
      }
      #pragma unroll
      for (int ni = 0; ni < 4; ni++) {
        int r = wcol + ni * 16 + lid;
        int slot = ((kk >> 3) + quad) ^ (lid & 7);
        bfr[ni] = *(const bf16x8*)&Bs[r * 64 + slot * 8];
      }
      #pragma unroll
      for (int mi = 0; mi < 4; mi++)
        #pragma unroll
        for (int ni = 0; ni < 4; ni++)
          acc[mi][ni] = __builtin_amdgcn_mfma_f32_16x16x32_bf16(af[mi], bfr[ni], acc[mi][ni], 0, 0, 0);
    }
    __syncthreads();
  }

  #pragma unroll
  for (int mi = 0; mi < 4; mi++) {
    #pragma unroll
    for (int ni = 0; ni < 4; ni++) {
      int col = n0 + wcol + ni * 16 + lid;
      if (col >= N) continue;
      #pragma unroll
      for (int r = 0; r < 4; r++) {
        int row = m0 + wrow + mi * 16 + quad * 4 + r;
        float v = acc[mi][ni][r];
        if (EPI == 1) v = sigmoidf_(v + bias[col]);
        if (EPI == 2) { float xx = v + bias[col]; v = fmaxf(xx, 0.f) + log1pf(expf(-fabsf(xx))); }
        if (EPI == 4) ((unsigned short*)C)[(size_t)row * N + col] = f2bf(v);
        else          C[(size_t)row * N + col] = v;
      }
    }
  }
}

// ---------------- x_proj split-K GEMM: (8192,2048) x (96,2048)^T ----------------
__global__ __launch_bounds__(256) void gemm_xk_k(
    const unsigned short* __restrict__ A, const unsigned short* __restrict__ Bw,
    float* __restrict__ slab, int M, int K, int KS)
{
  __shared__ __align__(16) unsigned short As[128 * 64];
  __shared__ __align__(16) unsigned short Bs[128 * 64];
  const int tid = threadIdx.x;
  const int m0 = blockIdx.x * 128;
  const int kslice = blockIdx.y;
  const int w = tid >> 6, lane = tid & 63;
  const int wrow = (w >> 1) * 64, wcol = (w & 1) * 64;
  const int quad = lane >> 4, lid = lane & 15;

  const int srow = lane >> 3;
  const int schunk = (lane & 7) ^ srow;

  const unsigned short* Abase = A + (size_t)(m0 + w * 8 + srow) * K + schunk * 8;
  const unsigned short* Bbase[4];
  #pragma unroll
  for (int i = 0; i < 4; i++) {
    int rB = w * 8 + i * 32 + srow;
    if (rB > XKN - 1) rB = XKN - 1;
    Bbase[i] = Bw + (size_t)rB * K + schunk * 8;
  }

  f32x4 acc[4][4] = {};
  const int kbeg = kslice * KS, kend = kbeg + KS;

  for (int k0 = kbeg; k0 < kend; k0 += 64) {
    #pragma unroll
    for (int i = 0; i < 4; i++) {
      int rA = w * 8 + i * 32;
      __builtin_amdgcn_global_load_lds(
          (const AS1 unsigned int*)(Abase + (size_t)i * 32 * K + k0),
          (AS3 unsigned int*)&As[rA * 64], 16, 0, 0);
      __builtin_amdgcn_global_load_lds(
          (const AS1 unsigned int*)(Bbase[i] + k0),
          (AS3 unsigned int*)&Bs[rA * 64], 16, 0, 0);
    }
    __syncthreads();
    #pragma unroll
    for (int kk = 0; kk < 64; kk += 32) {
      bf16x8 af[4], bfr[4];
      #pragma unroll
      for (int mi = 0; mi < 4; mi++) {
        int r = wrow + mi * 16 + lid;
        int slot = ((kk >> 3) + quad) ^ (lid & 7);
        af[mi] = *(const bf16x8*)&As[r * 64 + slot * 8];
      }
      #pragma unroll
      for (int ni = 0; ni < 4; ni++) {
        int r = wcol + ni * 16 + lid;
        int slot = ((kk >> 3) + quad) ^ (lid & 7);
        bfr[ni] = *(const bf16x8*)&Bs[r * 64 + slot * 8];
      }
      #pragma unroll
      for (int mi = 0; mi < 4; mi++)
        #pragma unroll
        for (int ni = 0; ni < 4; ni++)
          acc[mi][ni] = __builtin_amdgcn_mfma_f32_16x16x32_bf16(af[mi], bfr[ni], acc[mi][ni], 0, 0, 0);
    }
    __syncthreads();
  }

  float* Cs = slab + (size_t)kslice * M * XKN;
  #pragma unroll
  for (int mi = 0; mi < 4; mi++) {
    #pragma unroll
    for (int ni = 0; ni < 4; ni++) {
      int col = wcol + ni * 16 + lid;
      if (col >= XKN) continue;
      #pragma unroll
      for (int r = 0; r < 4; r++) {
        int row = m0 + wrow + mi * 16 + quad * 4 + r;
        Cs[(size_t)row * XKN + col] = acc[mi][ni][r];
      }
    }
  }
}

// ---------------- x_proj reduce: dbl = sum of 4 slabs; dt slice -> bf16 ----------------
__global__ void xproj_reduce_k(const float* __restrict__ slab, float* __restrict__ dbl,
                               unsigned short* __restrict__ dt_bf)
{
  int i = blockIdx.x * blockDim.x + threadIdx.x;   // over 8192*96
  if (i >= NROWS * XKN) return;
  const size_t S = (size_t)NROWS * XKN;
  float s = slab[i] + slab[i + S] + slab[i + 2 * S] + slab[i + 3 * S];
  dbl[i] = s;
  int row = i / XKN, col = i - row * XKN;
  if (col < 64) dt_bf[(size_t)row * 64 + col] = f2bf(s);
}

// ---------------- causal depthwise conv (K=4) + SiLU, bf16 in/out, x4 vectorized ----------------
__global__ void conv_silu_k(const unsigned short* __restrict__ u_r, const float* __restrict__ w,
                            const float* __restrict__ cb, unsigned short* __restrict__ uc_bf)
{
  int idx = blockIdx.x * blockDim.x + threadIdx.x;  // over B*L*DINNER/4
  if (idx >= BATCH * L_SEQ * DINNER / 4) return;
  int dd = idx & (DINNER / 4 - 1);
  int l = (idx >> 9) & (L_SEQ - 1);
  int b = idx >> 19;
  int d = dd * 4;
  float4 wv[4];
  #pragma unroll
  for (int j = 0; j < 4; j++) wv[j] = ((const float4*)w)[d + j];   // w[d+j][0..3]
  float4 cbv = *(const float4*)&cb[d];
  float acc[4] = {cbv.x, cbv.y, cbv.z, cbv.w};
  size_t rb = ((size_t)b * L_SEQ + l) * (2 * DINNER) + d;
  {
    ushort4 uv = *(const ushort4*)&u_r[rb];
    acc[0] += wv[0].w * bf2f(uv.x); acc[1] += wv[1].w * bf2f(uv.y);
    acc[2] += wv[2].w * bf2f(uv.z); acc[3] += wv[3].w * bf2f(uv.w);
  }
  if (l >= 1) {
    ushort4 uv = *(const ushort4*)&u_r[rb - (size_t)(2 * DINNER)];
    acc[0] += wv[0].z * bf2f(uv.x); acc[1] += wv[1].z * bf2f(uv.y);
    acc[2] += wv[2].z * bf2f(uv.z); acc[3] += wv[3].z * bf2f(uv.w);
  }
  if (l >= 2) {
    ushort4 uv = *(const ushort4*)&u_r[rb - (size_t)2 * (2 * DINNER)];
    acc[0] += wv[0].y * bf2f(uv.x); acc[1] += wv[1].y * bf2f(uv.y);
    acc[2] += wv[2].y * bf2f(uv.z); acc[3] += wv[3].y * bf2f(uv.w);
  }
  if (l >= 3) {
    ushort4 uv = *(const ushort4*)&u_r[rb - (size_t)3 * (2 * DINNER)];
    acc[0] += wv[0].x * bf2f(uv.x); acc[1] += wv[1].x * bf2f(uv.y);
    acc[2] += wv[2].x * bf2f(uv.z); acc[3] += wv[3].x * bf2f(uv.w);
  }
  ushort4 o;
  o.x = f2bf(acc[0] * sigmoidf_(acc[0]));
  o.y = f2bf(acc[1] * sigmoidf_(acc[1]));
  o.z = f2bf(acc[2] * sigmoidf_(acc[2]));
  o.w = f2bf(acc[3] * sigmoidf_(acc[3]));
  *(ushort4*)&uc_bf[((size_t)(b * L_SEQ + l)) * DINNER + d] = o;
}

// ---------------- A2 precompute: a2t[n][d] = -exp(A_log[d][n]) * log2(e) ----------------
__global__ void a2_k(const float* __restrict__ Alog, float* __restrict__ a2t)
{
  int i = blockIdx.x * blockDim.x + threadIdx.x;   // over 2048*16
  if (i >= DINNER * NSTATE) return;
  int d = i >> 4, n = i & 15;
  a2t[n * DINNER + d] = -expf(Alog[i]) * 1.4426950408889634f;
}

// ---------------- chunked scan pass 1: per-chunk aggregates (P, q) with h0=0 ----------------
__global__ __launch_bounds__(64) void scan1_k(
    const float* __restrict__ dlt, const unsigned short* __restrict__ uc,
    const float* __restrict__ dbl, const float* __restrict__ a2t,
    float* __restrict__ Pbuf, float* __restrict__ Qbuf)
{
  int c = blockIdx.x;            // chunk
  int dg = blockIdx.y;           // d-group of 64
  int b = blockIdx.z;
  int d = dg * 64 + threadIdx.x;
  float a2[NSTATE], P[NSTATE], q[NSTATE];
  #pragma unroll
  for (int n = 0; n < NSTATE; n++) {
    a2[n] = a2t[n * DINNER + d];
    P[n] = 1.f; q[n] = 0.f;
  }
  size_t base = ((size_t)(b * L_SEQ + c * CH)) * DINNER + d;
  const float* bc = dbl + (size_t)(b * L_SEQ + c * CH) * XKN + 64;
  for (int t = 0; t < CH; t++) {
    float dl = dlt[base];
    float du = dl * bf2f(uc[base]);
    #pragma unroll
    for (int n = 0; n < NSTATE; n++) {
      float dA = exp2f(dl * a2[n]);
      q[n] = dA * q[n] + du * bc[n];
      P[n] *= dA;
    }
    base += DINNER;
    bc += XKN;
  }
  size_t ob = ((size_t)((b * NCH + c) * NSTATE)) * DINNER + d;
  #pragma unroll
  for (int n = 0; n < NSTATE; n++) {
    Pbuf[ob + (size_t)n * DINNER] = P[n];
    Qbuf[ob + (size_t)n * DINNER] = q[n];
  }
}

// ---------------- chunked scan carry: sequential combine over chunks ----------------
__global__ void scan_carry_k(const float* __restrict__ Pbuf, float* __restrict__ Qbuf)
{
  int idx = blockIdx.x * blockDim.x + threadIdx.x;  // over 8*16*2048 = 262144
  if (idx >= BATCH * NSTATE * DINNER) return;
  int d = idx & (DINNER - 1);
  int n = (idx >> 11) & 15;
  int b = idx >> 15;
  float h = 0.f;
  for (int c = 0; c < NCH; c++) {
    size_t o = ((size_t)((b * NCH + c) * NSTATE + n)) * DINNER + d;
    float P = Pbuf[o];
    float q = Qbuf[o];
    Qbuf[o] = h;
    h = P * h + q;
  }
}

// ---------------- chunked scan pass 2 + gate fused ----------------
// Replays with true h_init, then applies (y + u*D) * silu(r) and writes bf16.
__global__ __launch_bounds__(64) void scan2_k(
    const float* __restrict__ dlt, const unsigned short* __restrict__ uc,
    const float* __restrict__ dbl, const float* __restrict__ a2t,
    const float* __restrict__ Qbuf, const unsigned short* __restrict__ u_r,
    const float* __restrict__ Dp, unsigned short* __restrict__ ybf)
{
  int c = blockIdx.x;
  int dg = blockIdx.y;
  int b = blockIdx.z;
  int d = dg * 64 + threadIdx.x;
  float a2[NSTATE], h[NSTATE];
  size_t ob = ((size_t)((b * NCH + c) * NSTATE)) * DINNER + d;
  #pragma unroll
  for (int n = 0; n < NSTATE; n++) {
    a2[n] = a2t[n * DINNER + d];
    h[n] = Qbuf[ob + (size_t)n * DINNER];
  }
  float Dd = Dp[d];
  size_t base = ((size_t)(b * L_SEQ + c * CH)) * DINNER + d;
  const float* bc = dbl + (size_t)(b * L_SEQ + c * CH) * XKN + 64;
  const unsigned short* rp = u_r + (size_t)(b * L_SEQ + c * CH) * (2 * DINNER) + DINNER + d;
  for (int t = 0; t < CH; t++) {
    float dl = dlt[base];
    float uval = bf2f(uc[base]);
    float du = dl * uval;
    float yv = 0.f;
    #pragma unroll
    for (int n = 0; n < NSTATE; n++) {
      float dA = exp2f(dl * a2[n]);
      h[n] = dA * h[n] + du * bc[n];
      yv += h[n] * bc[NSTATE + n];
    }
    float rv = bf2f(*rp);
    float val = (yv + uval * Dd) * (rv * sigmoidf_(rv));
    ybf[base] = f2bf(val);
    base += DINNER;
    bc += XKN;
    rp += 2 * DINNER;
  }
}

// ---------------- residual + LN1 -> bf16 (bf16 inputs) ----------------
__global__ __launch_bounds__(256) void ln1_k(
    const unsigned short* __restrict__ mamba, const unsigned short* __restrict__ item,
    const float* __restrict__ g, const float* __restrict__ bta,
    unsigned short* __restrict__ out_bf)
{
  __shared__ float sbuf[4];
  int i = blockIdx.x;
  int t = threadIdx.x;
  size_t rb = (size_t)i * 1024 + t * 4;
  ushort4 mv = *(const ushort4*)&mamba[rb];
  ushort4 iv = *(const ushort4*)&item[rb];
  float vx = bf2f(mv.x) + bf2f(iv.x);
  float vy = bf2f(mv.y) + bf2f(iv.y);
  float vz = bf2f(mv.z) + bf2f(iv.z);
  float vw = bf2f(mv.w) + bf2f(iv.w);
  float tot = blk_sum(vx + vy + vz + vw, sbuf);
  float mean = tot * (1.f / 1024.f);
  float dx = vx - mean, dy = vy - mean, dz = vz - mean, dw = vw - mean;
  float var = blk_sum(dx*dx + dy*dy + dz*dz + dw*dw, sbuf) * (1.f / 1024.f);
  float rstd = rsqrtf(var + 1e-12f);
  float vals[4] = {dx, dy, dz, dw};
  #pragma unroll
  for (int j = 0; j < 4; j++) {
    int c = t * 4 + j;
    out_bf[(size_t)i * 1024 + c] = f2bf(vals[j] * rstd * g[c] + bta[c]);
  }
}

// ---------------- launch ----------------
extern "C" void kernel_launch(void* const* d_in, const int* in_sizes, int n_in,
                              void* d_out, int out_size, void* d_ws, size_t ws_size,
                              hipStream_t stream)
{
  (void)in_sizes; (void)n_in; (void)out_size; (void)ws_size;
  const int*   x     = (const int*)d_in[0];
  const int*   qid   = (const int*)d_in[1];
  const float* emb   = (const float*)d_in[2];
  const float* qc    = (const float*)d_in[3];
  const float* ln0g  = (const float*)d_in[4];
  const float* ln0b  = (const float*)d_in[5];
  const float* w_in  = (const float*)d_in[6];
  const float* convw = (const float*)d_in[7];
  const float* convb = (const float*)d_in[8];
  const float* w_x   = (const float*)d_in[9];
  const float* w_dt  = (const float*)d_in[10];
  const float* dtb   = (const float*)d_in[11];
  const float* Alog  = (const float*)d_in[12];
  const float* Dp    = (const float*)d_in[13];
  const float* w_out = (const float*)d_in[14];
  const float* ln1g  = (const float*)d_in[15];
  const float* ln1b  = (const float*)d_in[16];
  const float* w_fc  = (const float*)d_in[17];
  const float* fcb   = (const float*)d_in[18];
  float* out = (float*)d_out;

  char* base = (char*)d_ws;
  size_t off = 0;
  auto carve = [&](size_t bytes) -> char* {
    char* p = base + off;
    off = (off + bytes + 255) & ~(size_t)255;
    return p;
  };
  unsigned short* item_bf = (unsigned short*)carve((size_t)NROWS * 1024 * 2);
  unsigned short* u_r     = (unsigned short*)carve((size_t)NROWS * 4096 * 2);
  unsigned short* ucbf    = (unsigned short*)carve((size_t)NROWS * 2048 * 2);
  float* dbl   = (float*)carve((size_t)NROWS * XKN * 4);
  float* dlt   = (float*)carve((size_t)NROWS * 2048 * 4);
  float* mamba = (float*)carve((size_t)NROWS * 1024 * 4);
  unsigned short* bfbuf  = (unsigned short*)carve((size_t)NROWS * 2048 * 2);
  unsigned short* bw_in  = (unsigned short*)carve((size_t)4096 * 1024 * 2);
  unsigned short* bw_x   = (unsigned short*)carve((size_t)XKN * 2048 * 2);
  unsigned short* bw_dt  = (unsigned short*)carve((size_t)2048 * 64 * 2);
  unsigned short* bw_out = (unsigned short*)carve((size_t)1024 * 2048 * 2);
  unsigned short* bw_fc  = (unsigned short*)carve((size_t)4000 * 1024 * 2);
  float* a2t   = (float*)carve((size_t)DINNER * NSTATE * 4);

  // Aliasing plan (all hazards separated by stream ordering):
  //   slab   <- dlt           x_proj partials (12.6 MB), dead after reduce;
  //                           dt_proj then overwrites dlt
  //   dt_bf  <- (u16*)mamba   written by reduce, read by dt_proj, dead after
  //   Pbuf   <- mamba         scan1 writes (over dead dt_bf), carry reads, dead
  //   Qbuf   <- (f32*)bfbuf   scan1 writes, carry rewrites, scan2 reads, dead
  //   y_bf   <- (u16*)mamba   scan2 writes (over dead Pbuf), out_proj A
  //   mamba_out <- u_r        out_proj C bf16 (u_r fully dead after scan2)
  //   ln_bf  <- bfbuf         ln1 writes (over dead Qbuf), fc A
  float* slab = dlt;
  unsigned short* dt_bf = (unsigned short*)mamba;
  float* Pbuf = mamba;
  float* Qbuf = (float*)bfbuf;
  unsigned short* y_bf = (unsigned short*)mamba;
  unsigned short* mamba_out = u_r;

  auto cv = [&](const float* s, unsigned short* dst, int n) {
    cast_bf16_k<<<(n + 255) / 256, 256, 0, stream>>>(s, dst, n);
  };
  cv(w_in,  bw_in,  4096 * 1024);
  cv(w_x,   bw_x,   XKN * 2048);
  cv(w_dt,  bw_dt,  2048 * 64);
  cv(w_out, bw_out, 1024 * 2048);
  cv(w_fc,  bw_fc,  4000 * 1024);
  a2_k<<<(DINNER * NSTATE + 255) / 256, 256, 0, stream>>>(Alog, a2t);

  // 1. embedding gather + concat + LN0 -> bf16
  embed_ln0_k<<<NROWS, 256, 0, stream>>>(x, qid, emb, qc, ln0g, ln0b, item_bf);

  // 2. in_proj: (8192,1024) x (4096,1024)^T -> u_r (bf16)
  gemm_bt_k<4><<<dim3(64, 32), 256, 0, stream>>>(item_bf, bw_in, (float*)u_r, nullptr, NROWS, 4096, 1024);

  // 3. conv + silu (bf16 in/out)
  conv_silu_k<<<(NROWS * DINNER / 4) / 256, 256, 0, stream>>>(u_r, convw, convb, ucbf);

  // 4. x_proj split-K (4 slices, 256 blocks) + reduce (also emits dt bf16 slice)
  gemm_xk_k<<<dim3(64, 4), 256, 0, stream>>>(ucbf, bw_x, slab, NROWS, 2048, 512);
  xproj_reduce_k<<<(NROWS * XKN) / 256, 256, 0, stream>>>(slab, dbl, dt_bf);

  // 5. dt_proj: (8192,64) x (2048,64)^T -> softplus(acc + dt_bias) -> dlt (f32)
  gemm_bt_k<2><<<dim3(64, 16), 256, 0, stream>>>(dt_bf, bw_dt, dlt, dtb, NROWS, 2048, 64);

  // 6. chunked selective scan (CH=64)
  scan1_k<<<dim3(NCH, 32, BATCH), 64, 0, stream>>>(dlt, ucbf, dbl, a2t, Pbuf, Qbuf);
  scan_carry_k<<<(BATCH * NSTATE * DINNER) / 256, 256, 0, stream>>>(Pbuf, Qbuf);
  // 7. scan pass 2 + gate fused -> y_bf
  scan2_k<<<dim3(NCH, 32, BATCH), 64, 0, stream>>>(dlt, ucbf, dbl, a2t, Qbuf, u_r, Dp, y_bf);

  // 8. out_proj: (8192,2048) x (1024,2048)^T -> mamba_out bf16 (=u_r region)
  gemm_bt_k<4><<<dim3(64, 8), 256, 0, stream>>>(y_bf, bw_out, (float*)mamba_out, nullptr, NROWS, 1024, 2048);

  // 9. residual + LN1 -> bf16
  ln1_k<<<NROWS, 256, 0, stream>>>(mamba_out, item_bf, ln1g, ln1b, bfbuf);

  // 10. fc + sigmoid -> out (f32, required)
  gemm_bt_k<1><<<dim3(64, 32), 256, 0, stream>>>(bfbuf, bw_fc, out, fcb, NROWS, 4000, 1024);
}